// Round 5
// baseline (414.954 us; speedup 1.0000x reference)
//
#include <hip/hip_runtime.h>

#define GN 100000
#define GE 3200000
#define CAP 128
#define NB 782          // coarse buckets: src >> 7, 128 nodes each
#define CHUNK 4096      // edges per bin-pass block

typedef __attribute__((ext_vector_type(8))) _Float16 f16x8;
typedef __attribute__((ext_vector_type(4))) _Float16 half4_t;
typedef __attribute__((ext_vector_type(2))) __fp16 fp16x2_raw;   // cvt_pkrtz native return type
typedef __attribute__((ext_vector_type(4))) float f32x4;

__device__ __forceinline__ unsigned pk2(float a, float b) {
    fp16x2_raw p = __builtin_amdgcn_cvt_pkrtz(a, b);
    return __builtin_bit_cast(unsigned, p);
}

// ---------------- W prep: w fp32 [256][128] -> wT f16 [128][256] ----------------
__global__ __launch_bounds__(256) void wprep_kernel(const float* __restrict__ w,
                                                    _Float16* __restrict__ wT) {
    int flat4 = blockIdx.x * 256 + threadIdx.x;     // 0..8191
    if (flat4 >= 256 * 128 / 4) return;
    int k  = flat4 >> 5;
    int n4 = (flat4 & 31) * 4;
    float4 v = ((const float4*)w)[flat4];
    wT[(size_t)(n4 + 0) * 256 + k] = (_Float16)v.x;
    wT[(size_t)(n4 + 1) * 256 + k] = (_Float16)v.y;
    wT[(size_t)(n4 + 2) * 256 + k] = (_Float16)v.z;
    wT[(size_t)(n4 + 3) * 256 + k] = (_Float16)v.w;
}

// ---------------- GEMM: h = x @ W via f16 MFMA; scores fused in epilogue ----------------
__global__ __launch_bounds__(256) void gemm_kernel(const float* __restrict__ x,
                                                   const _Float16* __restrict__ wT,
                                                   const float* __restrict__ a,
                                                   _Float16* __restrict__ hq,
                                                   float* __restrict__ s_l,
                                                   float* __restrict__ s_r) {
    __shared__ _Float16 As[128][40];    // 80 B row pitch (multiple of 16 B)
    const int tid  = threadIdx.x;
    const int lane = tid & 63, wid = tid >> 6;
    const int l16  = lane & 15, quad = lane >> 4;
    const int wm   = (wid >> 1) * 64, wn = (wid & 1) * 64;
    const int bm   = blockIdx.x * 128;

    f32x4 acc[4][4] = {};

    const int arow = tid >> 1, ahalf = tid & 1;
    int gr = bm + arow; if (gr >= GN) gr = GN - 1;   // clamp loads; stores guarded
    const float* xrow = x + (size_t)gr * 256 + ahalf * 16;

    for (int k0 = 0; k0 < 256; k0 += 32) {
        float4 f0 = *(const float4*)(xrow + k0);
        float4 f1 = *(const float4*)(xrow + k0 + 4);
        float4 f2 = *(const float4*)(xrow + k0 + 8);
        float4 f3 = *(const float4*)(xrow + k0 + 12);
        uint4 lo = {pk2(f0.x, f0.y), pk2(f0.z, f0.w), pk2(f1.x, f1.y), pk2(f1.z, f1.w)};
        uint4 hi = {pk2(f2.x, f2.y), pk2(f2.z, f2.w), pk2(f3.x, f3.y), pk2(f3.z, f3.w)};
        __syncthreads();                     // protect previous tile's readers
        *(uint4*)&As[arow][ahalf * 16]     = lo;
        *(uint4*)&As[arow][ahalf * 16 + 8] = hi;
        __syncthreads();
        f16x8 af[4], bfr[4];
#pragma unroll
        for (int t = 0; t < 4; ++t) {
            af[t]  = *(const f16x8*)&As[wm + t * 16 + l16][quad * 8];
            bfr[t] = *(const f16x8*)(wT + (size_t)(wn + t * 16 + l16) * 256 + k0 + quad * 8);
        }
#pragma unroll
        for (int ti = 0; ti < 4; ++ti)
#pragma unroll
            for (int tj = 0; tj < 4; ++tj)
                acc[ti][tj] = __builtin_amdgcn_mfma_f32_16x16x32_f16(af[ti], bfr[tj], acc[ti][tj], 0, 0, 0);
    }

    float alv[4], arv[4];
#pragma unroll
    for (int tj = 0; tj < 4; ++tj) {
        alv[tj] = a[wn + tj * 16 + l16];
        arv[tj] = a[128 + wn + tj * 16 + l16];
    }
#pragma unroll
    for (int ti = 0; ti < 4; ++ti) {
        float slp[4], srp[4];
#pragma unroll
        for (int r = 0; r < 4; ++r) {
            int row = bm + wm + ti * 16 + quad * 4 + r;
            float v0 = acc[ti][0][r], v1 = acc[ti][1][r], v2 = acc[ti][2][r], v3 = acc[ti][3][r];
            if (row < GN) {
                _Float16* hp = hq + (size_t)row * 128 + wn + l16;
                hp[0]  = (_Float16)v0;
                hp[16] = (_Float16)v1;
                hp[32] = (_Float16)v2;
                hp[48] = (_Float16)v3;
            }
            slp[r] = v0 * alv[0] + v1 * alv[1] + v2 * alv[2] + v3 * alv[3];
            srp[r] = v0 * arv[0] + v1 * arv[1] + v2 * arv[2] + v3 * arv[3];
        }
#pragma unroll
        for (int off = 1; off < 16; off <<= 1)
#pragma unroll
            for (int r = 0; r < 4; ++r) {
                slp[r] += __shfl_xor(slp[r], off, 64);
                srp[r] += __shfl_xor(srp[r], off, 64);
            }
        if (l16 == 0) {
#pragma unroll
            for (int r = 0; r < 4; ++r) {
                int row = bm + wm + ti * 16 + quad * 4 + r;
                if (row < GN) {
                    atomicAdd(&s_l[row], slp[r]);
                    atomicAdd(&s_r[row], srp[r]);
                }
            }
        }
    }
}

// ---------------- CSR build, pass 1: coarse bucket histogram ----------------
__global__ __launch_bounds__(256) void bhist_kernel(const int* __restrict__ src,
                                                    int* __restrict__ bcnt) {
    __shared__ int bh[NB];
    const int tid = threadIdx.x;
    for (int j = tid; j < NB; j += 256) bh[j] = 0;
    __syncthreads();
    const int base = blockIdx.x * CHUNK;
    const int cnt = min(CHUNK, GE - base);
    for (int i = tid; i < cnt; i += 256) atomicAdd(&bh[src[base + i] >> 7], 1);
    __syncthreads();
    for (int j = tid; j < NB; j += 256)
        if (bh[j]) atomicAdd(&bcnt[j], bh[j]);
}

// ---------------- CSR build, pass 2: bucket exclusive scan (one wave) ----------------
__global__ __launch_bounds__(64) void bscan_kernel(const int* __restrict__ bcnt,
                                                   int* __restrict__ bbase,
                                                   int* __restrict__ bcursor) {
    __shared__ int arr[NB];
    const int tid = threadIdx.x;
    for (int j = tid; j < NB; j += 64) arr[j] = bcnt[j];
    __syncthreads();
    int carry = 0;
    for (int b0 = 0; b0 < NB; b0 += 64) {
        int idx = b0 + tid;
        int v = (idx < NB) ? arr[idx] : 0;
        int x = v;
#pragma unroll
        for (int off = 1; off < 64; off <<= 1) {
            int y = __shfl_up(x, off, 64);
            if (tid >= off) x += y;
        }
        if (idx < NB) { bbase[idx] = carry + x - v; bcursor[idx] = carry + x - v; }
        carry += __shfl(x, 63, 64);
    }
    if (tid == 0) bbase[NB] = carry;
}

// ---------------- CSR build, pass 3: per-chunk counting sort -> coalesced runs ----------------
// entry = (srcLow7 << 17) | dst17
__global__ __launch_bounds__(256) void bin_kernel(const int* __restrict__ ei,
                                                  int* __restrict__ bcursor,
                                                  unsigned* __restrict__ binned) {
    __shared__ int h_cnt[NB];
    __shared__ int h_base[NB + 1];
    __shared__ int h_gpos[NB];
    __shared__ int h_cur[NB];
    __shared__ unsigned sbuf[CHUNK];
    __shared__ unsigned short bkt[CHUNK];
    const int tid = threadIdx.x;
    const int base = blockIdx.x * CHUNK;
    const int cnt = min(CHUNK, GE - base);

    int srcv[CHUNK / 256], dstv[CHUNK / 256];
#pragma unroll
    for (int i = 0; i < CHUNK / 256; ++i) {
        int idx = tid + i * 256;
        if (idx < cnt) { srcv[i] = ei[base + idx]; dstv[i] = ei[GE + base + idx]; }
        else srcv[i] = -1;
    }
    for (int j = tid; j < NB; j += 256) h_cnt[j] = 0;
    __syncthreads();
#pragma unroll
    for (int i = 0; i < CHUNK / 256; ++i)
        if (srcv[i] >= 0) atomicAdd(&h_cnt[srcv[i] >> 7], 1);
    __syncthreads();
    if (tid < 64) {                      // wave0 exclusive scan of h_cnt -> h_base
        int carry = 0;
        for (int b0 = 0; b0 < NB; b0 += 64) {
            int idx = b0 + tid;
            int v = (idx < NB) ? h_cnt[idx] : 0;
            int x = v;
#pragma unroll
            for (int off = 1; off < 64; off <<= 1) {
                int y = __shfl_up(x, off, 64);
                if (tid >= off) x += y;
            }
            if (idx < NB) h_base[idx] = carry + x - v;
            carry += __shfl(x, 63, 64);
        }
        if (tid == 0) h_base[NB] = carry;
    }
    __syncthreads();
    for (int j = tid; j < NB; j += 256) {
        h_cur[j] = h_base[j];
        int c = h_cnt[j];
        if (c) h_gpos[j] = atomicAdd(&bcursor[j], c);   // reserve run in bucket region
    }
    __syncthreads();
#pragma unroll
    for (int i = 0; i < CHUNK / 256; ++i)
        if (srcv[i] >= 0) {
            int b = srcv[i] >> 7;
            int p = atomicAdd(&h_cur[b], 1);
            sbuf[p] = ((unsigned)(srcv[i] & 127) << 17) | (unsigned)dstv[i];
            bkt[p] = (unsigned short)b;
        }
    __syncthreads();
    for (int p = tid; p < cnt; p += 256) {   // coalesced run copy-out, direct bucket lookup
        int b = bkt[p];
        binned[h_gpos[b] + (p - h_base[b])] = sbuf[p];
    }
}

// ---------------- CSR build, pass 4: per-bucket fine scatter (exclusive 16KB window) ----------------
__global__ __launch_bounds__(256) void fine_kernel(const unsigned* __restrict__ binned,
                                                   const int* __restrict__ bbase,
                                                   int* __restrict__ rowptr,
                                                   int* __restrict__ adj) {
    __shared__ int n_cnt[128];
    __shared__ int n_base[129];
    __shared__ int n_cur[128];
    const int b = blockIdx.x;
    const int tid = threadIdx.x;
    const int node0 = b << 7;
    const int nn = min(128, GN - node0);
    const int beg = bbase[b], end = bbase[b + 1];
    if (tid < 128) n_cnt[tid] = 0;
    __syncthreads();
    for (int p = beg + tid; p < end; p += 256)
        atomicAdd(&n_cnt[binned[p] >> 17], 1);
    __syncthreads();
    if (tid < 64) {
        int carry = 0;
        for (int b0 = 0; b0 < 128; b0 += 64) {
            int idx = b0 + tid;
            int v = n_cnt[idx];
            int x = v;
#pragma unroll
            for (int off = 1; off < 64; off <<= 1) {
                int y = __shfl_up(x, off, 64);
                if (tid >= off) x += y;
            }
            n_base[idx] = carry + x - v;
            carry += __shfl(x, 63, 64);
        }
        if (tid == 0) n_base[128] = carry;
    }
    __syncthreads();
    if (tid < nn) rowptr[node0 + tid] = beg + n_base[tid];
    if (b == NB - 1 && tid == 0) rowptr[GN] = end;
    if (tid < 128) n_cur[tid] = n_base[tid];
    __syncthreads();
    for (int p = beg + tid; p < end; p += 256) {
        unsigned e = binned[p];
        int s = e >> 17, d = (int)(e & 0x1FFFFu);
        int pos = atomicAdd(&n_cur[s], 1);
        adj[beg + pos] = d;
    }
}

// ---------------- per-node softmax + weighted aggregation (f16 h) ----------------
// one wave/node, wave-private LDS, no barriers. Fast path (deg<=CAP):
//   A: e + max (1 fmax/edge); B: 1 exp/edge, sum; C: 2 edges/wave-pass via
//   32-lane x half4 (8 B/lane); normalization folded into the final store.
__global__ __launch_bounds__(256) void aggregate_kernel(const half4_t* __restrict__ h4,
                                                        const float* __restrict__ s_l,
                                                        const float* __restrict__ s_r,
                                                        const int* __restrict__ rowptr,
                                                        const int* __restrict__ adj,
                                                        float* __restrict__ out) {
    __shared__ uint2 s_ed[4][CAP + 4];     // .x = dst, .y = e then alpha(un-normalized)
    const int wid = threadIdx.x >> 6, lane = threadIdx.x & 63;
    const int node = blockIdx.x * 4 + wid;            // grid = GN/4 exactly
    const int beg = rowptr[node], end = rowptr[node + 1];
    const int deg = end - beg;
    const float sl = s_l[node];

    if (deg <= CAP) {
        float m = -1e30f;
        for (int j = lane; j < deg; j += 64) {
            int dst = adj[beg + j];
            float e = sl + s_r[dst];
            e = (e >= 0.f) ? e : 0.2f * e;
            uint2 ed; ed.x = (unsigned)dst; ed.y = __float_as_uint(e);
            s_ed[wid][j] = ed;
            m = fmaxf(m, e);
        }
#pragma unroll
        for (int off = 32; off; off >>= 1) m = fmaxf(m, __shfl_xor(m, off, 64));
        float d = 0.f;
        for (int j = lane; j < deg; j += 64) {
            float al = __expf(__uint_as_float(s_ed[wid][j].y) - m);
            d += al;
            ((unsigned*)&s_ed[wid][j])[1] = __float_as_uint(al);
        }
#pragma unroll
        for (int off = 32; off; off >>= 1) d += __shfl_xor(d, off, 64);
        const float inv = 1.f / (d + 1e-16f);
        const int n4 = (deg + 3) & ~3;
        if (lane < n4 - deg) { uint2 z; z.x = 0u; z.y = 0u; s_ed[wid][deg + lane] = z; }
        const int hh = lane >> 5, fl = lane & 31;
        float ax = 0.f, ay = 0.f, az = 0.f, aw = 0.f;
        for (int j = 0; j < n4; j += 4) {
            uint2 ea = s_ed[wid][j + hh];
            uint2 eb = s_ed[wid][j + hh + 2];
            half4_t va = h4[(ea.x << 5) | fl];
            half4_t vb = h4[(eb.x << 5) | fl];
            float aa = __uint_as_float(ea.y), ab = __uint_as_float(eb.y);
            ax += aa * (float)va[0] + ab * (float)vb[0];
            ay += aa * (float)va[1] + ab * (float)vb[1];
            az += aa * (float)va[2] + ab * (float)vb[2];
            aw += aa * (float)va[3] + ab * (float)vb[3];
        }
        ax += __shfl_xor(ax, 32, 64);
        ay += __shfl_xor(ay, 32, 64);
        az += __shfl_xor(az, 32, 64);
        aw += __shfl_xor(aw, 32, 64);
        if (hh == 0) {
            float4 v = {ax * inv, ay * inv, az * inv, aw * inv};
            *(float4*)(out + ((size_t)node << 7) + (fl << 2)) = v;
        }
    } else {
        // rare slow path: full online softmax, per-edge recompute
        const unsigned* h32 = (const unsigned*)h4;
        float m = -1e30f, d = 0.f;
        for (int j = lane; j < deg; j += 64) {
            int dst = adj[beg + j];
            float e = sl + s_r[dst];
            e = (e >= 0.f) ? e : 0.2f * e;
            float mn = fmaxf(m, e);
            d = d * __expf(m - mn) + __expf(e - mn);
            m = mn;
        }
#pragma unroll
        for (int off = 32; off; off >>= 1) {
            float m2 = __shfl_xor(m, off, 64);
            float d2 = __shfl_xor(d, off, 64);
            float mn = fmaxf(m, m2);
            d = d * __expf(m - mn) + d2 * __expf(m2 - mn);
            m = mn;
        }
        float inv = 1.f / (d + 1e-16f);
        float2 acc = {0.f, 0.f};
        for (int j = 0; j < deg; ++j) {
            int dst = adj[beg + j];
            float e = sl + s_r[dst];
            e = (e >= 0.f) ? e : 0.2f * e;
            float al = __expf(e - m);
            unsigned v = h32[((unsigned)dst << 6) | lane];
            acc.x += al * (float)__builtin_bit_cast(_Float16, (unsigned short)(v & 0xffffu));
            acc.y += al * (float)__builtin_bit_cast(_Float16, (unsigned short)(v >> 16));
        }
        float2 o = {acc.x * inv, acc.y * inv};
        ((float2*)out)[(size_t)node * 64 + lane] = o;
    }
}

extern "C" void kernel_launch(void* const* d_in, const int* in_sizes, int n_in,
                              void* d_out, int out_size, void* d_ws, size_t ws_size,
                              hipStream_t stream) {
    const float* x  = (const float*)d_in[0];
    const int*   ei = (const int*)d_in[1];      // [0,E) = src, [E,2E) = dst
    const float* w  = (const float*)d_in[2];
    const float* a  = (const float*)d_in[3];
    float* out = (float*)d_out;

    // workspace layout (4-byte words)
    _Float16* hq   = (_Float16*)d_ws;                        // GN*128 f16
    float* s_l     = (float*)(hq + (size_t)GN * 128);        // GN
    float* s_r     = s_l + GN;                               // GN
    int*   bcnt    = (int*)(s_r + GN);                       // NB (zeroed with s_l/s_r)
    int*   bbase   = bcnt + NB;                              // NB+1
    int*   bcursor = bbase + NB + 1;                         // NB
    int*   rowptr  = bcursor + NB;                           // GN+1
    unsigned* binned = (unsigned*)(rowptr + GN + 1);         // GE
    int*   adj     = (int*)(binned + GE);                    // GE
    _Float16* wT   = (_Float16*)(adj + GE);                  // 128*256 f16

    (void)hipMemsetAsync(s_l, 0, (size_t)(2 * GN + NB) * sizeof(float), stream);  // s_l, s_r, bcnt

    wprep_kernel<<<32, 256, 0, stream>>>(w, wT);
    gemm_kernel<<<(GN + 127) / 128, 256, 0, stream>>>(x, wT, a, hq, s_l, s_r);
    bhist_kernel<<<(GE + CHUNK - 1) / CHUNK, 256, 0, stream>>>(ei, bcnt);
    bscan_kernel<<<1, 64, 0, stream>>>(bcnt, bbase, bcursor);
    bin_kernel<<<(GE + CHUNK - 1) / CHUNK, 256, 0, stream>>>(ei, bcursor, binned);
    fine_kernel<<<NB, 256, 0, stream>>>(binned, bbase, rowptr, adj);
    aggregate_kernel<<<GN / 4, 256, 0, stream>>>((const half4_t*)hq, s_l, s_r, rowptr, adj, out);
}